// Round 5
// baseline (197.695 us; speedup 1.0000x reference)
//
#include <hip/hip_runtime.h>
#include <stdint.h>

// DCNv2 forward, MI355X. Pipeline:
//  K0 prep_weights : W -> WB bf16 MFMA-B order; p_weight -> PWs bf16 (N=32 pad)
//  K1 transpose_x  : x NCHW -> xt NHWC fp32
//  K2 offset_conv_sk : split-K (S=8) implicit-im2col bf16 MFMA conv, BM=64,
//                      XCD-swizzled (each XCD owns one half-batch -> xt slice
//                      fits its 4MB L2), writes fp32 partials Pbuf[s][m][32]
//  K3 sample_fused : reduces Pbuf partials (wave-uniform scalar loads) + bias
//                    + sigmoid, then bilinear (fp32) * mask -> A bf16 [m][kk];
//                    XCD-swizzled to the same half-batch regions as K2 so both
//                    xt taps and Pbuf stay in the local XCD L2.
//  K4 main_gemm    : 128x64 tile, BK=64, ping-pong LDS dbuf, 36 iters.
// Workspace: 112.7 MB of the 256 MiB d_ws (fill evidence: 256 MiB poison).

#define NB 4
#define CIN 256
#define COUT 256
#define HWS 4096      // H*W
#define MTOT 16384    // B*H*W
#define KTOT 2304     // CIN*9
#define SPLITK 8

typedef __attribute__((ext_vector_type(8))) short bf16x8;
typedef __attribute__((ext_vector_type(4))) float f32x4;

__device__ __forceinline__ unsigned short f2bf(float f) {
  unsigned int u = __float_as_uint(f);
  unsigned int r = (u + 0x7fffu + ((u >> 16) & 1u)) >> 16;
  return (unsigned short)r;
}

__device__ __forceinline__ void gload_lds16(const void* g, void* l) {
  __builtin_amdgcn_global_load_lds((const __attribute__((address_space(1))) void*)g,
                                   (__attribute__((address_space(3))) void*)l, 16, 0, 0);
}

// ---------------- K0: weight prep ----------------
__global__ __launch_bounds__(256) void prep_weights(const float* __restrict__ w,
                                                    const float* __restrict__ pw,
                                                    unsigned short* __restrict__ WB,
                                                    unsigned short* __restrict__ PWs) {
  int idx = blockIdx.x * 256 + threadIdx.x;
  if (idx < KTOT * COUT) {
    int f = idx;
    int t_ = f & 7;
    int rest = f >> 3;
    int o = rest & 255;
    int kk = (rest >> 8) * 8 + t_;
    int k = kk >> 8, c = kk & 255;
    WB[f] = f2bf(w[o * KTOT + c * 9 + k]);
  } else {
    int f2 = idx - KTOT * COUT;   // < 2304*32
    int t_ = f2 & 7;
    int rest = f2 >> 3;
    int j = rest & 31;
    int kk = (rest >> 5) * 8 + t_;
    int k = kk >> 8, c = kk & 255;
    float v = (j < 27) ? pw[j * KTOT + c * 9 + k] : 0.0f;
    PWs[f2] = f2bf(v);
  }
}

// ---------------- K1: NCHW -> NHWC transpose ----------------
__global__ __launch_bounds__(256) void transpose_x(const float* __restrict__ x,
                                                   float* __restrict__ xt) {
  __shared__ float tile[32][33];
  int b = blockIdx.z;
  int hw0 = blockIdx.x * 32;
  int c0 = blockIdx.y * 32;
  int tx = threadIdx.x, ty = threadIdx.y;
  for (int i = ty; i < 32; i += 8)
    tile[i][tx] = x[(size_t)(b * CIN + c0 + i) * HWS + hw0 + tx];
  __syncthreads();
  for (int r = ty; r < 32; r += 8)
    xt[(size_t)(b * HWS + hw0 + r) * CIN + c0 + tx] = tile[tx][r];
}

// ---------------- K2: offset conv, split-K, BM=64, XCD-swizzled ----------------
__global__ __launch_bounds__(256) void offset_conv_sk(const float* __restrict__ xt,
                                                      const unsigned short* __restrict__ PWs,
                                                      float* __restrict__ Pbuf) {
  __shared__ unsigned short Al[64 * 32];   // 4 KB
  __shared__ unsigned short Bl[1024];      // 2 KB
  int tid = threadIdx.x;
  int lane = tid & 63, wv = tid >> 6;
  // XCD swizzle: bid%8 (XCD id heuristic) picks a half-batch region so this
  // XCD's xt working set (~2.1 MB) fits its 4 MB L2.
  int mt = (blockIdx.x & 7) * 32 + (blockIdx.x >> 3);
  int m0 = mt * 64;
  int s = blockIdx.y;
  int b = m0 >> 12;
  int hw0 = m0 & 4095;
  f32x4 acc[2] = {};

  for (int tt = 0; tt < 72 / SPLITK; ++tt) {
    int t = s * (72 / SPLITK) + tt;
    int k = t >> 3, c0 = (t & 7) * 32;
    int dyk = k / 3 - 1;
    int dxk = k % 3 - 1;
    __syncthreads();
    *(uint2*)&Bl[tid * 4] = *(const uint2*)(PWs + (size_t)t * 1024 + tid * 4);
    {
      int r = tid >> 2;
      int q = (tid & 3) * 8;
      int hw = hw0 + r;
      int h = hw >> 6, wwp = hw & 63;
      int y = h + dyk, xx = wwp + dxk;
      float4 v0 = make_float4(0.f, 0.f, 0.f, 0.f);
      float4 v1 = make_float4(0.f, 0.f, 0.f, 0.f);
      if ((unsigned)y < 64u && (unsigned)xx < 64u) {
        const float* p = xt + ((size_t)((b << 12) + (y << 6) + xx) << 8) + c0 + q;
        v0 = *(const float4*)p;
        v1 = *(const float4*)(p + 4);
      }
      unsigned short u[8];
      u[0] = f2bf(v0.x); u[1] = f2bf(v0.y); u[2] = f2bf(v0.z); u[3] = f2bf(v0.w);
      u[4] = f2bf(v1.x); u[5] = f2bf(v1.y); u[6] = f2bf(v1.z); u[7] = f2bf(v1.w);
      *(uint4*)&Al[r * 32 + q] = *(const uint4*)u;
    }
    __syncthreads();
    int row = lane & 15, quad = lane >> 4;
    bf16x8 af = *(const bf16x8*)&Al[(wv * 16 + row) * 32 + quad * 8];
    for (int j = 0; j < 2; ++j) {
      bf16x8 bfr = *(const bf16x8*)&Bl[(quad * 32 + j * 16 + row) * 8];
      acc[j] = __builtin_amdgcn_mfma_f32_16x16x32_bf16(af, bfr, acc[j], 0, 0, 0);
    }
  }

  int row = lane & 15, quad = lane >> 4;
  for (int j = 0; j < 2; ++j) {
    int n = j * 16 + row;
    for (int r_ = 0; r_ < 4; ++r_) {
      int m = m0 + wv * 16 + quad * 4 + r_;
      Pbuf[((size_t)s * MTOT + m) * 32 + n] = acc[j][r_];
    }
  }
}

// ---------------- K3: fused reduce + bilinear sampling -> A bf16 ----------------
// One wave per (m, k) task. XCD-swizzled: bid&7 selects the same half-batch
// region K2 produced there, so Pbuf partials AND xt taps are local-L2 hits.
__global__ __launch_bounds__(256) void sample_fused(const float* __restrict__ xt,
                                                    const float* __restrict__ Pbuf,
                                                    const float* __restrict__ p_bias,
                                                    unsigned short* __restrict__ A) {
  int wv = threadIdx.x >> 6;
  int lane = threadIdx.x & 63;
  int reg = blockIdx.x & 7;               // half-batch region == XCD
  int tr = (blockIdx.x >> 3) * 4 + wv;    // [0, 18432) task within region
  int ml = tr / 9;
  int k = tr - ml * 9;
  int m = reg * 2048 + ml;
  int b = m >> 12, hw = m & 4095, h = hw >> 6, ww = hw & 63;

  // reduce split-K partials (all wave-uniform -> scalar path)
  float dy = p_bias[2 * k];
  float dx = p_bias[2 * k + 1];
  float mv = p_bias[18 + k];
#pragma unroll
  for (int s = 0; s < SPLITK; ++s) {
    const float* p = Pbuf + ((size_t)s * MTOT + m) * 32;
    dy += p[2 * k];
    dx += p[2 * k + 1];
    mv += p[18 + k];
  }
  float mk = 1.0f / (1.0f + __expf(-mv));

  float py = (float)(h - 1 + k / 3) + dy;
  float px = (float)(ww - 1 + k % 3) + dx;
  float y0f = floorf(py), x0f = floorf(px);
  float ay = py - y0f, ax = px - x0f;
  int y0 = (int)y0f, x0 = (int)x0f;

  float w00 = (1.f - ay) * (1.f - ax) * mk;
  float w01 = (1.f - ay) * ax * mk;
  float w10 = ay * (1.f - ax) * mk;
  float w11 = ay * ax * mk;

  float vy0 = ((unsigned)y0 < 64u) ? 1.f : 0.f;
  float vy1 = ((unsigned)(y0 + 1) < 64u) ? 1.f : 0.f;
  float vx0 = ((unsigned)x0 < 64u) ? 1.f : 0.f;
  float vx1 = ((unsigned)(x0 + 1) < 64u) ? 1.f : 0.f;
  w00 *= vy0 * vx0; w01 *= vy0 * vx1; w10 *= vy1 * vx0; w11 *= vy1 * vx1;

  int yc0 = min(max(y0, 0), 63), yc1 = min(max(y0 + 1, 0), 63);
  int xc0 = min(max(x0, 0), 63), xc1 = min(max(x0 + 1, 0), 63);

  const float4* base = (const float4*)(xt + ((size_t)b << 12) * CIN);
  float4 t00 = base[(yc0 * 64 + xc0) * 64 + lane];
  float4 t01 = base[(yc0 * 64 + xc1) * 64 + lane];
  float4 t10 = base[(yc1 * 64 + xc0) * 64 + lane];
  float4 t11 = base[(yc1 * 64 + xc1) * 64 + lane];

  float4 r;
  r.x = w00 * t00.x + w01 * t01.x + w10 * t10.x + w11 * t11.x;
  r.y = w00 * t00.y + w01 * t01.y + w10 * t10.y + w11 * t11.y;
  r.z = w00 * t00.z + w01 * t01.z + w10 * t10.z + w11 * t11.z;
  r.w = w00 * t00.w + w01 * t01.w + w10 * t10.w + w11 * t11.w;

  ushort4 o;
  o.x = f2bf(r.x); o.y = f2bf(r.y); o.z = f2bf(r.z); o.w = f2bf(r.w);
  *(ushort4*)(A + (size_t)m * KTOT + k * 256 + lane * 4) = o;
}

// ---------------- K4: main GEMM 128x64, BK=64 (2x32), ping-pong dbuf ----------------
__global__ __launch_bounds__(256) void main_gemm(const unsigned short* __restrict__ Amat,
                                                 const unsigned short* __restrict__ WB,
                                                 const float* __restrict__ bias,
                                                 float* __restrict__ out) {
  __shared__ unsigned short Al[2][2][128 * 32];  // 32 KB
  __shared__ unsigned short Bl[2][8 * 64 * 8];   // 16 KB
  int tid = threadIdx.x;
  int lane = tid & 63, wv = tid >> 6;
  int m0 = blockIdx.x * 128;
  int n0 = blockIdx.y * 64;
  int wm = wv * 32;
  f32x4 acc[2][4] = {};

  auto stage = [&](int t, int buf) {
#pragma unroll
    for (int p = 0; p < 4; ++p) {
      int li = p * 256 + tid;
      int ks = li >> 9;
      int li2 = li & 511;
      int row = li2 >> 2, ch = li2 & 3;
      const unsigned short* src = Amat + (size_t)(m0 + row) * KTOT + t * 64 + ks * 32 + ch * 8;
      gload_lds16(src, &Al[buf][ks][li2 * 8]);
    }
#pragma unroll
    for (int p = 0; p < 2; ++p) {
      int li = p * 256 + tid;
      int kb8 = li >> 6, col = li & 63;
      const unsigned short* src = WB + ((size_t)(t * 8 + kb8) * 256 + n0 + col) * 8;
      gload_lds16(src, &Bl[buf][li * 8]);
    }
  };

  stage(0, 0);
  __syncthreads();

  int row = lane & 15, quad = lane >> 4;
  for (int t = 0; t < 36; ++t) {
    int cur = t & 1;
    if (t < 35) stage(t + 1, cur ^ 1);
#pragma unroll
    for (int ks = 0; ks < 2; ++ks) {
      bf16x8 af[2], bfr[4];
#pragma unroll
      for (int i = 0; i < 2; ++i)
        af[i] = *(const bf16x8*)&Al[cur][ks][(wm + i * 16 + row) * 32 + quad * 8];
#pragma unroll
      for (int j = 0; j < 4; ++j)
        bfr[j] = *(const bf16x8*)&Bl[cur][((ks * 4 + quad) * 64 + j * 16 + row) * 8];
#pragma unroll
      for (int i = 0; i < 2; ++i)
#pragma unroll
        for (int j = 0; j < 4; ++j)
          acc[i][j] = __builtin_amdgcn_mfma_f32_16x16x32_bf16(af[i], bfr[j], acc[i][j], 0, 0, 0);
    }
    __syncthreads();
  }

  int b = m0 >> 12, hw0 = m0 & 4095;
  for (int j = 0; j < 4; ++j) {
    int o = n0 + j * 16 + row;
    float bo = bias[o];
    for (int i = 0; i < 2; ++i) {
      int hw = hw0 + wm + i * 16 + quad * 4;
      float4 v;
      v.x = acc[i][j][0] + bo;
      v.y = acc[i][j][1] + bo;
      v.z = acc[i][j][2] + bo;
      v.w = acc[i][j][3] + bo;
      *(float4*)(out + (((size_t)(b * COUT + o)) << 12) + hw) = v;
    }
  }
}

// ---------------- launch ----------------
extern "C" void kernel_launch(void* const* d_in, const int* in_sizes, int n_in,
                              void* d_out, int out_size, void* d_ws, size_t ws_size,
                              hipStream_t stream) {
  const float* x        = (const float*)d_in[0];
  const float* weight   = (const float*)d_in[1];
  const float* bias     = (const float*)d_in[2];
  const float* p_weight = (const float*)d_in[3];
  const float* p_bias   = (const float*)d_in[4];
  float* out = (float*)d_out;
  char* ws = (char*)d_ws;

  // workspace layout (bytes); total 112,738,304 (d_ws is 256 MiB per the
  // harness poison-fill WRITE_SIZE). Pbuf no longer aliases Amat.
  const size_t OFF_XT   = 0;                          // 16,777,216  fp32 NHWC x
  const size_t OFF_WB   = 16777216;                   //  1,179,648  bf16
  const size_t OFF_PW   = OFF_WB + 1179648;           //    147,456  bf16
  const size_t OFF_A    = OFF_PW + 147456;            // 75,497,472  bf16
  const size_t OFF_P    = OFF_A + 75497472;           // 16,777,216  fp32 partials

  float* xt   = (float*)(ws + OFF_XT);
  unsigned short* WB   = (unsigned short*)(ws + OFF_WB);
  unsigned short* PWs  = (unsigned short*)(ws + OFF_PW);
  unsigned short* Amat = (unsigned short*)(ws + OFF_A);
  float* Pbuf = (float*)(ws + OFF_P);

  prep_weights<<<(KTOT * COUT + KTOT * 32) / 256, 256, 0, stream>>>(weight, p_weight, WB, PWs);
  transpose_x<<<dim3(128, 8, 4), dim3(32, 8), 0, stream>>>(x, xt);
  offset_conv_sk<<<dim3(MTOT / 64, SPLITK), 256, 0, stream>>>(xt, PWs, Pbuf);
  sample_fused<<<(MTOT * 9) / 4, 256, 0, stream>>>(xt, Pbuf, p_bias, Amat);
  main_gemm<<<dim3(MTOT / 128, COUT / 64), 256, 0, stream>>>(Amat, WB, bias, out);
}

// Round 6
// 162.196 us; speedup vs baseline: 1.2189x; 1.2189x over previous
//
#include <hip/hip_runtime.h>
#include <stdint.h>

// DCNv2 forward, MI355X. Pipeline:
//  K0 prep_weights : W -> WB bf16 MFMA-B order; p_weight -> PWs bf16 (N=32 pad)
//  K1 transpose_x  : x NCHW -> xt NHWC fp32
//  K2 offset_conv_sk : split-K (S=8) implicit-im2col bf16 MFMA conv, BM=64,
//                      XCD-swizzled, writes fp32 partials Pbuf[s][m][32]
//  K2b reduce_offsets: sum 8 partials + bias -> dy/dx/sigmoid(mask)  [R4 revert:
//                      doing this per-sample-wave was 64-lane-redundant -> 76us]
//  K3 sample9      : ONE WAVE PER m, all 9 taps (amortizes offset loads + addr
//                    math 9x), bilinear fp32 * mask -> A bf16 [m][k*256+c];
//                    XCD-swizzled to K2's half-batch regions (FETCH 17MB proof).
//  K4 main_gemm    : 128x64 tile, BK=64, ping-pong LDS dbuf, 36 iters.
// Workspace: 112.7 MB of the 256 MiB d_ws.

#define NB 4
#define CIN 256
#define COUT 256
#define HWS 4096      // H*W
#define MTOT 16384    // B*H*W
#define KTOT 2304     // CIN*9
#define SPLITK 8

typedef __attribute__((ext_vector_type(8))) short bf16x8;
typedef __attribute__((ext_vector_type(4))) float f32x4;

__device__ __forceinline__ unsigned short f2bf(float f) {
  unsigned int u = __float_as_uint(f);
  unsigned int r = (u + 0x7fffu + ((u >> 16) & 1u)) >> 16;
  return (unsigned short)r;
}

__device__ __forceinline__ void gload_lds16(const void* g, void* l) {
  __builtin_amdgcn_global_load_lds((const __attribute__((address_space(1))) void*)g,
                                   (__attribute__((address_space(3))) void*)l, 16, 0, 0);
}

// ---------------- K0: weight prep ----------------
__global__ __launch_bounds__(256) void prep_weights(const float* __restrict__ w,
                                                    const float* __restrict__ pw,
                                                    unsigned short* __restrict__ WB,
                                                    unsigned short* __restrict__ PWs) {
  int idx = blockIdx.x * 256 + threadIdx.x;
  if (idx < KTOT * COUT) {
    int f = idx;
    int t_ = f & 7;
    int rest = f >> 3;
    int o = rest & 255;
    int kk = (rest >> 8) * 8 + t_;
    int k = kk >> 8, c = kk & 255;
    WB[f] = f2bf(w[o * KTOT + c * 9 + k]);
  } else {
    int f2 = idx - KTOT * COUT;   // < 2304*32
    int t_ = f2 & 7;
    int rest = f2 >> 3;
    int j = rest & 31;
    int kk = (rest >> 5) * 8 + t_;
    int k = kk >> 8, c = kk & 255;
    float v = (j < 27) ? pw[j * KTOT + c * 9 + k] : 0.0f;
    PWs[f2] = f2bf(v);
  }
}

// ---------------- K1: NCHW -> NHWC transpose ----------------
__global__ __launch_bounds__(256) void transpose_x(const float* __restrict__ x,
                                                   float* __restrict__ xt) {
  __shared__ float tile[32][33];
  int b = blockIdx.z;
  int hw0 = blockIdx.x * 32;
  int c0 = blockIdx.y * 32;
  int tx = threadIdx.x, ty = threadIdx.y;
  for (int i = ty; i < 32; i += 8)
    tile[i][tx] = x[(size_t)(b * CIN + c0 + i) * HWS + hw0 + tx];
  __syncthreads();
  for (int r = ty; r < 32; r += 8)
    xt[(size_t)(b * HWS + hw0 + r) * CIN + c0 + tx] = tile[tx][r];
}

// ---------------- K2: offset conv, split-K, BM=64, XCD-swizzled ----------------
__global__ __launch_bounds__(256) void offset_conv_sk(const float* __restrict__ xt,
                                                      const unsigned short* __restrict__ PWs,
                                                      float* __restrict__ Pbuf) {
  __shared__ unsigned short Al[64 * 32];   // 4 KB
  __shared__ unsigned short Bl[1024];      // 2 KB
  int tid = threadIdx.x;
  int lane = tid & 63, wv = tid >> 6;
  int mt = (blockIdx.x & 7) * 32 + (blockIdx.x >> 3);
  int m0 = mt * 64;
  int s = blockIdx.y;
  int b = m0 >> 12;
  int hw0 = m0 & 4095;
  f32x4 acc[2] = {};

  for (int tt = 0; tt < 72 / SPLITK; ++tt) {
    int t = s * (72 / SPLITK) + tt;
    int k = t >> 3, c0 = (t & 7) * 32;
    int dyk = k / 3 - 1;
    int dxk = k % 3 - 1;
    __syncthreads();
    *(uint2*)&Bl[tid * 4] = *(const uint2*)(PWs + (size_t)t * 1024 + tid * 4);
    {
      int r = tid >> 2;
      int q = (tid & 3) * 8;
      int hw = hw0 + r;
      int h = hw >> 6, wwp = hw & 63;
      int y = h + dyk, xx = wwp + dxk;
      float4 v0 = make_float4(0.f, 0.f, 0.f, 0.f);
      float4 v1 = make_float4(0.f, 0.f, 0.f, 0.f);
      if ((unsigned)y < 64u && (unsigned)xx < 64u) {
        const float* p = xt + ((size_t)((b << 12) + (y << 6) + xx) << 8) + c0 + q;
        v0 = *(const float4*)p;
        v1 = *(const float4*)(p + 4);
      }
      unsigned short u[8];
      u[0] = f2bf(v0.x); u[1] = f2bf(v0.y); u[2] = f2bf(v0.z); u[3] = f2bf(v0.w);
      u[4] = f2bf(v1.x); u[5] = f2bf(v1.y); u[6] = f2bf(v1.z); u[7] = f2bf(v1.w);
      *(uint4*)&Al[r * 32 + q] = *(const uint4*)u;
    }
    __syncthreads();
    int row = lane & 15, quad = lane >> 4;
    bf16x8 af = *(const bf16x8*)&Al[(wv * 16 + row) * 32 + quad * 8];
    for (int j = 0; j < 2; ++j) {
      bf16x8 bfr = *(const bf16x8*)&Bl[(quad * 32 + j * 16 + row) * 8];
      acc[j] = __builtin_amdgcn_mfma_f32_16x16x32_bf16(af, bfr, acc[j], 0, 0, 0);
    }
  }

  int row = lane & 15, quad = lane >> 4;
  for (int j = 0; j < 2; ++j) {
    int n = j * 16 + row;
    for (int r_ = 0; r_ < 4; ++r_) {
      int m = m0 + wv * 16 + quad * 4 + r_;
      Pbuf[((size_t)s * MTOT + m) * 32 + n] = acc[j][r_];
    }
  }
}

// ---------------- K2b: reduce split-K partials -> dy/dx/mask ----------------
__global__ __launch_bounds__(256) void reduce_offsets(const float* __restrict__ Pbuf,
                                                      const float* __restrict__ p_bias,
                                                      float* __restrict__ dyA,
                                                      float* __restrict__ dxA,
                                                      float* __restrict__ maskA) {
  int idx = blockIdx.x * 256 + threadIdx.x;  // m*32+n
  int n = idx & 31;
  int m = idx >> 5;
  float v = 0.f;
#pragma unroll
  for (int s = 0; s < SPLITK; ++s)
    v += Pbuf[(size_t)s * MTOT * 32 + idx];
  if (n < 27) {
    v += p_bias[n];
    if (n < 18) {
      if ((n & 1) == 0) dyA[m * 9 + (n >> 1)] = v;
      else              dxA[m * 9 + (n >> 1)] = v;
    } else {
      maskA[m * 9 + (n - 18)] = 1.0f / (1.0f + __expf(-v));
    }
  }
}

// ---------------- K3: bilinear sampling, ONE WAVE PER m (9 taps) ----------------
__global__ __launch_bounds__(256) void sample9(const float* __restrict__ xt,
                                               const float* __restrict__ dyA,
                                               const float* __restrict__ dxA,
                                               const float* __restrict__ maskA,
                                               unsigned short* __restrict__ A) {
  int wv = threadIdx.x >> 6;
  int lane = threadIdx.x & 63;
  int reg = blockIdx.x & 7;                       // half-batch region == XCD
  int m = reg * 2048 + (blockIdx.x >> 3) * 4 + wv;  // grid.x = MTOT/4
  int b = m >> 12, hw = m & 4095, h = hw >> 6, ww = hw & 63;

  const float4* base = (const float4*)(xt + ((size_t)b << 12) * CIN);
  unsigned short* outp = A + (size_t)m * KTOT + lane * 4;

#pragma unroll
  for (int k = 0; k < 9; ++k) {
    float dy = dyA[m * 9 + k];
    float dx = dxA[m * 9 + k];
    float mk = maskA[m * 9 + k];

    float py = (float)(h - 1 + k / 3) + dy;
    float px = (float)(ww - 1 + k % 3) + dx;
    float y0f = floorf(py), x0f = floorf(px);
    float ay = py - y0f, ax = px - x0f;
    int y0 = (int)y0f, x0 = (int)x0f;

    float w00 = (1.f - ay) * (1.f - ax) * mk;
    float w01 = (1.f - ay) * ax * mk;
    float w10 = ay * (1.f - ax) * mk;
    float w11 = ay * ax * mk;

    float vy0 = ((unsigned)y0 < 64u) ? 1.f : 0.f;
    float vy1 = ((unsigned)(y0 + 1) < 64u) ? 1.f : 0.f;
    float vx0 = ((unsigned)x0 < 64u) ? 1.f : 0.f;
    float vx1 = ((unsigned)(x0 + 1) < 64u) ? 1.f : 0.f;
    w00 *= vy0 * vx0; w01 *= vy0 * vx1; w10 *= vy1 * vx0; w11 *= vy1 * vx1;

    int yc0 = min(max(y0, 0), 63), yc1 = min(max(y0 + 1, 0), 63);
    int xc0 = min(max(x0, 0), 63), xc1 = min(max(x0 + 1, 0), 63);

    float4 t00 = base[(yc0 * 64 + xc0) * 64 + lane];
    float4 t01 = base[(yc0 * 64 + xc1) * 64 + lane];
    float4 t10 = base[(yc1 * 64 + xc0) * 64 + lane];
    float4 t11 = base[(yc1 * 64 + xc1) * 64 + lane];

    float4 r;
    r.x = w00 * t00.x + w01 * t01.x + w10 * t10.x + w11 * t11.x;
    r.y = w00 * t00.y + w01 * t01.y + w10 * t10.y + w11 * t11.y;
    r.z = w00 * t00.z + w01 * t01.z + w10 * t10.z + w11 * t11.z;
    r.w = w00 * t00.w + w01 * t01.w + w10 * t10.w + w11 * t11.w;

    ushort4 o;
    o.x = f2bf(r.x); o.y = f2bf(r.y); o.z = f2bf(r.z); o.w = f2bf(r.w);
    *(ushort4*)(outp + k * 256) = o;
  }
}

// ---------------- K4: main GEMM 128x64, BK=64 (2x32), ping-pong dbuf ----------------
__global__ __launch_bounds__(256) void main_gemm(const unsigned short* __restrict__ Amat,
                                                 const unsigned short* __restrict__ WB,
                                                 const float* __restrict__ bias,
                                                 float* __restrict__ out) {
  __shared__ unsigned short Al[2][2][128 * 32];  // 32 KB
  __shared__ unsigned short Bl[2][8 * 64 * 8];   // 16 KB
  int tid = threadIdx.x;
  int lane = tid & 63, wv = tid >> 6;
  int m0 = blockIdx.x * 128;
  int n0 = blockIdx.y * 64;
  int wm = wv * 32;
  f32x4 acc[2][4] = {};

  auto stage = [&](int t, int buf) {
#pragma unroll
    for (int p = 0; p < 4; ++p) {
      int li = p * 256 + tid;
      int ks = li >> 9;
      int li2 = li & 511;
      int row = li2 >> 2, ch = li2 & 3;
      const unsigned short* src = Amat + (size_t)(m0 + row) * KTOT + t * 64 + ks * 32 + ch * 8;
      gload_lds16(src, &Al[buf][ks][li2 * 8]);
    }
#pragma unroll
    for (int p = 0; p < 2; ++p) {
      int li = p * 256 + tid;
      int kb8 = li >> 6, col = li & 63;
      const unsigned short* src = WB + ((size_t)(t * 8 + kb8) * 256 + n0 + col) * 8;
      gload_lds16(src, &Bl[buf][li * 8]);
    }
  };

  stage(0, 0);
  __syncthreads();

  int row = lane & 15, quad = lane >> 4;
  for (int t = 0; t < 36; ++t) {
    int cur = t & 1;
    if (t < 35) stage(t + 1, cur ^ 1);
#pragma unroll
    for (int ks = 0; ks < 2; ++ks) {
      bf16x8 af[2], bfr[4];
#pragma unroll
      for (int i = 0; i < 2; ++i)
        af[i] = *(const bf16x8*)&Al[cur][ks][(wm + i * 16 + row) * 32 + quad * 8];
#pragma unroll
      for (int j = 0; j < 4; ++j)
        bfr[j] = *(const bf16x8*)&Bl[cur][((ks * 4 + quad) * 64 + j * 16 + row) * 8];
#pragma unroll
      for (int i = 0; i < 2; ++i)
#pragma unroll
        for (int j = 0; j < 4; ++j)
          acc[i][j] = __builtin_amdgcn_mfma_f32_16x16x32_bf16(af[i], bfr[j], acc[i][j], 0, 0, 0);
    }
    __syncthreads();
  }

  int b = m0 >> 12, hw0 = m0 & 4095;
  for (int j = 0; j < 4; ++j) {
    int o = n0 + j * 16 + row;
    float bo = bias[o];
    for (int i = 0; i < 2; ++i) {
      int hw = hw0 + wm + i * 16 + quad * 4;
      float4 v;
      v.x = acc[i][j][0] + bo;
      v.y = acc[i][j][1] + bo;
      v.z = acc[i][j][2] + bo;
      v.w = acc[i][j][3] + bo;
      *(float4*)(out + (((size_t)(b * COUT + o)) << 12) + hw) = v;
    }
  }
}

// ---------------- launch ----------------
extern "C" void kernel_launch(void* const* d_in, const int* in_sizes, int n_in,
                              void* d_out, int out_size, void* d_ws, size_t ws_size,
                              hipStream_t stream) {
  const float* x        = (const float*)d_in[0];
  const float* weight   = (const float*)d_in[1];
  const float* bias     = (const float*)d_in[2];
  const float* p_weight = (const float*)d_in[3];
  const float* p_bias   = (const float*)d_in[4];
  float* out = (float*)d_out;
  char* ws = (char*)d_ws;

  // workspace layout (bytes); total ~114.5 MB of 256 MiB d_ws.
  const size_t OFF_XT   = 0;                          // 16,777,216  fp32 NHWC x
  const size_t OFF_WB   = 16777216;                   //  1,179,648  bf16
  const size_t OFF_PW   = OFF_WB + 1179648;           //    147,456  bf16
  const size_t OFF_A    = OFF_PW + 147456;            // 75,497,472  bf16
  const size_t OFF_P    = OFF_A + 75497472;           // 16,777,216  fp32 partials
  const size_t OFF_DY   = OFF_P + 16777216;           //    589,824
  const size_t OFF_DX   = OFF_DY + 589824;            //    589,824
  const size_t OFF_MASK = OFF_DX + 589824;            //    589,824

  float* xt   = (float*)(ws + OFF_XT);
  unsigned short* WB   = (unsigned short*)(ws + OFF_WB);
  unsigned short* PWs  = (unsigned short*)(ws + OFF_PW);
  unsigned short* Amat = (unsigned short*)(ws + OFF_A);
  float* Pbuf = (float*)(ws + OFF_P);
  float* dyA  = (float*)(ws + OFF_DY);
  float* dxA  = (float*)(ws + OFF_DX);
  float* mskA = (float*)(ws + OFF_MASK);

  prep_weights<<<(KTOT * COUT + KTOT * 32) / 256, 256, 0, stream>>>(weight, p_weight, WB, PWs);
  transpose_x<<<dim3(128, 8, 4), dim3(32, 8), 0, stream>>>(x, xt);
  offset_conv_sk<<<dim3(MTOT / 64, SPLITK), 256, 0, stream>>>(xt, PWs, Pbuf);
  reduce_offsets<<<(MTOT * 32) / 256, 256, 0, stream>>>(Pbuf, p_bias, dyA, dxA, mskA);
  sample9<<<MTOT / 4, 256, 0, stream>>>(xt, dyA, dxA, mskA, Amat);
  main_gemm<<<dim3(MTOT / 128, COUT / 64), 256, 0, stream>>>(Amat, WB, bias, out);
}